// Round 1
// baseline (1192.825 us; speedup 1.0000x reference)
//
#include <hip/hip_runtime.h>

#define NN 10000
#define EE 320000
#define DD 256

// One wave (64 lanes) per edge: lane l handles dims [4l, 4l+4).
// agg must be pre-initialized (here: to x, fusing the +x of GIN eps=0).
__global__ __launch_bounds__(256) void scatter_kernel(
    const float* __restrict__ x,
    const int* __restrict__ src,
    const int* __restrict__ dst,
    float* __restrict__ agg)
{
    int wave = (int)((blockIdx.x * blockDim.x + threadIdx.x) >> 6);
    int lane = threadIdx.x & 63;
    if (wave >= EE) return;
    int s = src[wave];
    int d = dst[wave];
    const float4 v = *(const float4*)(x + (size_t)s * DD + lane * 4);
    float* ap = agg + (size_t)d * DD + lane * 4;
    atomicAdd(ap + 0, v.x);
    atomicAdd(ap + 1, v.y);
    atomicAdd(ap + 2, v.z);
    atomicAdd(ap + 3, v.w);
}

// C[M x 256] = act(A[M x 256] @ W[256 x 256] + bias)
// 64x64 tile, BK=16, 256 threads, 4x4 microtile per thread.
template <bool RELU>
__global__ __launch_bounds__(256) void gemm_kernel(
    const float* __restrict__ A,
    const float* __restrict__ W,
    const float* __restrict__ bias,
    float* __restrict__ C,
    int M)
{
    __shared__ float As[16][64];   // [k][m]
    __shared__ float Bs[16][64];   // [k][n]

    const int tid = threadIdx.x;
    const int m0 = blockIdx.y * 64;
    const int n0 = blockIdx.x * 64;
    const int tm = tid >> 4;        // 0..15
    const int tn = tid & 15;        // 0..15

    // loader indices
    const int la_m = tid >> 2;          // 0..63 (row within tile)
    const int la_k = (tid & 3) * 4;     // 0,4,8,12 (k offset, float4 along k)
    const int lb_k = tid >> 4;          // 0..15
    const int lb_n = (tid & 15) * 4;    // 0..60

    float acc[4][4] = {};

    for (int k0 = 0; k0 < 256; k0 += 16) {
        const int am = m0 + la_m;
        float4 a;
        if (am < M) {
            a = *(const float4*)(A + (size_t)am * 256 + k0 + la_k);
        } else {
            a = make_float4(0.f, 0.f, 0.f, 0.f);
        }
        const float4 b = *(const float4*)(W + (size_t)(k0 + lb_k) * 256 + n0 + lb_n);

        __syncthreads();   // protect previous tile's readers
        As[la_k + 0][la_m] = a.x;
        As[la_k + 1][la_m] = a.y;
        As[la_k + 2][la_m] = a.z;
        As[la_k + 3][la_m] = a.w;
        *(float4*)&Bs[lb_k][lb_n] = b;
        __syncthreads();

#pragma unroll
        for (int k = 0; k < 16; ++k) {
            const float4 av = *(const float4*)&As[k][tm * 4];
            const float4 bv = *(const float4*)&Bs[k][tn * 4];
            const float ar[4] = {av.x, av.y, av.z, av.w};
            const float br[4] = {bv.x, bv.y, bv.z, bv.w};
#pragma unroll
            for (int i = 0; i < 4; ++i)
#pragma unroll
                for (int j = 0; j < 4; ++j)
                    acc[i][j] = fmaf(ar[i], br[j], acc[i][j]);
        }
    }

    const int cm = m0 + tm * 4;
    const int cn = n0 + tn * 4;
    const float4 bb = *(const float4*)(bias + cn);
    const float br[4] = {bb.x, bb.y, bb.z, bb.w};
#pragma unroll
    for (int i = 0; i < 4; ++i) {
        if (cm + i < M) {
            float4 o;
            o.x = acc[i][0] + br[0];
            o.y = acc[i][1] + br[1];
            o.z = acc[i][2] + br[2];
            o.w = acc[i][3] + br[3];
            if (RELU) {
                o.x = fmaxf(o.x, 0.f);
                o.y = fmaxf(o.y, 0.f);
                o.z = fmaxf(o.z, 0.f);
                o.w = fmaxf(o.w, 0.f);
            }
            *(float4*)(C + (size_t)(cm + i) * 256 + cn) = o;
        }
    }
}

extern "C" void kernel_launch(void* const* d_in, const int* in_sizes, int n_in,
                              void* d_out, int out_size, void* d_ws, size_t ws_size,
                              hipStream_t stream)
{
    const float* x   = (const float*)d_in[0];
    const int*   ei  = (const int*)d_in[1];     // [2, E] row-major: src then dst
    const float* W1  = (const float*)d_in[2];
    const float* b1  = (const float*)d_in[3];
    const float* W2  = (const float*)d_in[4];
    const float* b2  = (const float*)d_in[5];
    float* out = (float*)d_out;

    const int E = in_sizes[1] / 2;
    const int* src = ei;
    const int* dst = ei + E;

    float* agg = (float*)d_ws;                              // N*256 floats
    float* h1  = (float*)((char*)d_ws + (size_t)NN * DD * sizeof(float));

    // agg = x  (fuses GIN's (1+eps)*x_i with eps=0)
    hipMemcpyAsync(agg, x, (size_t)NN * DD * sizeof(float),
                   hipMemcpyDeviceToDevice, stream);

    // agg[dst] += x[src]
    {
        const int waves_per_block = 4;                       // 256 threads
        const int blocks = (EE + waves_per_block - 1) / waves_per_block;
        scatter_kernel<<<blocks, 256, 0, stream>>>(x, src, dst, agg);
    }

    // h1 = relu(agg @ W1 + b1)
    {
        dim3 grid(DD / 64, (NN + 63) / 64);
        gemm_kernel<true><<<grid, 256, 0, stream>>>(agg, W1, b1, h1, NN);
    }

    // out = h1 @ W2 + b2
    {
        dim3 grid(DD / 64, (NN + 63) / 64);
        gemm_kernel<false><<<grid, 256, 0, stream>>>(h1, W2, b2, out, NN);
    }
}

// Round 2
// 225.296 us; speedup vs baseline: 5.2945x; 5.2945x over previous
//
#include <hip/hip_runtime.h>

#define NN 10000
#define EE 320000
#define DD 256

// ---------- CSR build ----------

__global__ __launch_bounds__(256) void count_kernel(
    const int* __restrict__ dst, int* __restrict__ counts)
{
    int e = blockIdx.x * blockDim.x + threadIdx.x;
    if (e < EE) atomicAdd(&counts[dst[e]], 1);
}

// Single-block exclusive scan over counts[NN] -> row_start[NN+1], cursor[NN]
__global__ __launch_bounds__(1024) void scan_kernel(
    const int* __restrict__ counts,
    int* __restrict__ row_start,
    int* __restrict__ cursor)
{
    __shared__ int smem[1024];
    __shared__ int s_carry;
    const int tid = threadIdx.x;
    if (tid == 0) s_carry = 0;
    __syncthreads();
    for (int base = 0; base < NN; base += 1024) {
        const int idx = base + tid;
        const int v = (idx < NN) ? counts[idx] : 0;
        smem[tid] = v;
        __syncthreads();
        // Hillis-Steele inclusive scan
        for (int off = 1; off < 1024; off <<= 1) {
            int t = (tid >= off) ? smem[tid - off] : 0;
            __syncthreads();
            smem[tid] += t;
            __syncthreads();
        }
        const int incl = smem[tid];
        const int excl = incl - v + s_carry;
        if (idx < NN) { row_start[idx] = excl; cursor[idx] = excl; }
        __syncthreads();                    // everyone done reading s_carry
        if (tid == 1023) s_carry += incl;   // chunk total
        __syncthreads();
    }
    if (tid == 0) row_start[NN] = s_carry;
}

__global__ __launch_bounds__(256) void fill_kernel(
    const int* __restrict__ src, const int* __restrict__ dst,
    int* __restrict__ cursor, int* __restrict__ sorted_src)
{
    int e = blockIdx.x * blockDim.x + threadIdx.x;
    if (e < EE) {
        int p = atomicAdd(&cursor[dst[e]], 1);
        sorted_src[p] = src[e];
    }
}

// ---------- gather-sum: agg[i] = x[i] + sum_{j in N(i)} x[j] ----------
// One wave per node; lane l owns dims [4l, 4l+4).
__global__ __launch_bounds__(256) void gather_kernel(
    const float* __restrict__ x,
    const int* __restrict__ row_start,
    const int* __restrict__ sorted_src,
    float* __restrict__ agg)
{
    const int wave = (int)((blockIdx.x * blockDim.x + threadIdx.x) >> 6);
    const int lane = threadIdx.x & 63;
    if (wave >= NN) return;
    const int beg = row_start[wave];
    const int end = row_start[wave + 1];
    const float4* xv = (const float4*)x;

    float4 acc = xv[(size_t)wave * 64 + lane];   // fuses the +x_i (eps=0)
    int j = beg;
    for (; j + 1 < end; j += 2) {                // 2-way unroll for load ILP
        const int s0 = sorted_src[j];
        const int s1 = sorted_src[j + 1];
        const float4 v0 = xv[(size_t)s0 * 64 + lane];
        const float4 v1 = xv[(size_t)s1 * 64 + lane];
        acc.x += v0.x + v1.x;
        acc.y += v0.y + v1.y;
        acc.z += v0.z + v1.z;
        acc.w += v0.w + v1.w;
    }
    if (j < end) {
        const int s0 = sorted_src[j];
        const float4 v0 = xv[(size_t)s0 * 64 + lane];
        acc.x += v0.x; acc.y += v0.y; acc.z += v0.z; acc.w += v0.w;
    }
    ((float4*)agg)[(size_t)wave * 64 + lane] = acc;
}

// ---------- GEMM: C[M x 256] = act(A @ W + bias) ----------
// 64x64 tile, BK=16, 256 threads, 4x4 microtile per thread.
template <bool RELU>
__global__ __launch_bounds__(256) void gemm_kernel(
    const float* __restrict__ A,
    const float* __restrict__ W,
    const float* __restrict__ bias,
    float* __restrict__ C,
    int M)
{
    __shared__ float As[16][64];   // [k][m]
    __shared__ float Bs[16][64];   // [k][n]

    const int tid = threadIdx.x;
    const int m0 = blockIdx.y * 64;
    const int n0 = blockIdx.x * 64;
    const int tm = tid >> 4;
    const int tn = tid & 15;

    const int la_m = tid >> 2;
    const int la_k = (tid & 3) * 4;
    const int lb_k = tid >> 4;
    const int lb_n = (tid & 15) * 4;

    float acc[4][4] = {};

    for (int k0 = 0; k0 < 256; k0 += 16) {
        const int am = m0 + la_m;
        float4 a;
        if (am < M) {
            a = *(const float4*)(A + (size_t)am * 256 + k0 + la_k);
        } else {
            a = make_float4(0.f, 0.f, 0.f, 0.f);
        }
        const float4 b = *(const float4*)(W + (size_t)(k0 + lb_k) * 256 + n0 + lb_n);

        __syncthreads();
        As[la_k + 0][la_m] = a.x;
        As[la_k + 1][la_m] = a.y;
        As[la_k + 2][la_m] = a.z;
        As[la_k + 3][la_m] = a.w;
        *(float4*)&Bs[lb_k][lb_n] = b;
        __syncthreads();

#pragma unroll
        for (int k = 0; k < 16; ++k) {
            const float4 av = *(const float4*)&As[k][tm * 4];
            const float4 bv = *(const float4*)&Bs[k][tn * 4];
            const float ar[4] = {av.x, av.y, av.z, av.w};
            const float br[4] = {bv.x, bv.y, bv.z, bv.w};
#pragma unroll
            for (int i = 0; i < 4; ++i)
#pragma unroll
                for (int j = 0; j < 4; ++j)
                    acc[i][j] = fmaf(ar[i], br[j], acc[i][j]);
        }
    }

    const int cm = m0 + tm * 4;
    const int cn = n0 + tn * 4;
    const float4 bb = *(const float4*)(bias + cn);
    const float br[4] = {bb.x, bb.y, bb.z, bb.w};
#pragma unroll
    for (int i = 0; i < 4; ++i) {
        if (cm + i < M) {
            float4 o;
            o.x = acc[i][0] + br[0];
            o.y = acc[i][1] + br[1];
            o.z = acc[i][2] + br[2];
            o.w = acc[i][3] + br[3];
            if (RELU) {
                o.x = fmaxf(o.x, 0.f);
                o.y = fmaxf(o.y, 0.f);
                o.z = fmaxf(o.z, 0.f);
                o.w = fmaxf(o.w, 0.f);
            }
            *(float4*)(C + (size_t)(cm + i) * 256 + cn) = o;
        }
    }
}

extern "C" void kernel_launch(void* const* d_in, const int* in_sizes, int n_in,
                              void* d_out, int out_size, void* d_ws, size_t ws_size,
                              hipStream_t stream)
{
    const float* x   = (const float*)d_in[0];
    const int*   ei  = (const int*)d_in[1];     // [2, E]: src row then dst row
    const float* W1  = (const float*)d_in[2];
    const float* b1  = (const float*)d_in[3];
    const float* W2  = (const float*)d_in[4];
    const float* b2  = (const float*)d_in[5];
    float* out = (float*)d_out;

    const int E = in_sizes[1] / 2;
    const int* src = ei;
    const int* dst = ei + E;

    // Workspace layout
    float* agg        = (float*)d_ws;                     // NN*DD
    float* h1         = agg + (size_t)NN * DD;            // NN*DD
    int*   counts     = (int*)(h1 + (size_t)NN * DD);     // NN (reused as cursor)
    int*   row_start  = counts + NN;                      // NN+1
    int*   sorted_src = row_start + NN + 1;               // E

    // --- CSR build ---
    hipMemsetAsync(counts, 0, NN * sizeof(int), stream);
    count_kernel<<<(EE + 255) / 256, 256, 0, stream>>>(dst, counts);
    scan_kernel<<<1, 1024, 0, stream>>>(counts, row_start, counts);
    fill_kernel<<<(EE + 255) / 256, 256, 0, stream>>>(src, dst, counts, sorted_src);

    // --- gather-sum (fuses +x) ---
    {
        const int waves_per_block = 4;   // 256 threads
        const int blocks = (NN + waves_per_block - 1) / waves_per_block;
        gather_kernel<<<blocks, 256, 0, stream>>>(x, row_start, sorted_src, agg);
    }

    // --- MLP ---
    {
        dim3 grid(DD / 64, (NN + 63) / 64);
        gemm_kernel<true><<<grid, 256, 0, stream>>>(agg, W1, b1, h1, NN);
        gemm_kernel<false><<<grid, 256, 0, stream>>>(h1, W2, b2, out, NN);
    }
    (void)E; (void)ws_size; (void)n_in; (void)out_size;
}

// Round 3
// 186.892 us; speedup vs baseline: 6.3824x; 1.2055x over previous
//
#include <hip/hip_runtime.h>

#define NN 10000
#define EE 320000
#define DD 256

typedef __attribute__((ext_vector_type(8))) short short8;
typedef __attribute__((ext_vector_type(4))) float f32x4;

// ---- bf16 helpers (bit-level, RNE) ----
__device__ __forceinline__ float bf_lo(unsigned u) { return __uint_as_float(u << 16); }
__device__ __forceinline__ float bf_hi(unsigned u) { return __uint_as_float(u & 0xffff0000u); }
__device__ __forceinline__ unsigned short f2bf(float f) {
    unsigned u = __float_as_uint(f);
    u += 0x7fffu + ((u >> 16) & 1u);   // round-to-nearest-even
    return (unsigned short)(u >> 16);
}

// ---- convert x fp32 -> bf16 (8 elems/thread) ----
__global__ __launch_bounds__(256) void convert_x_kernel(
    const float* __restrict__ x, unsigned short* __restrict__ xb)
{
    const int i = (blockIdx.x * blockDim.x + threadIdx.x) * 8;
    if (i >= NN * DD) return;
    const float4 a = *(const float4*)(x + i);
    const float4 b = *(const float4*)(x + i + 4);
    unsigned short o[8] = {f2bf(a.x), f2bf(a.y), f2bf(a.z), f2bf(a.w),
                           f2bf(b.x), f2bf(b.y), f2bf(b.z), f2bf(b.w)};
    *(short8*)(xb + i) = *(short8*)o;
}

// ---- convert+transpose W [k][n] fp32 -> Wt [n][k] bf16 ----
// grid (4,4,2) block (64,4); z selects (W1->W1t) or (W2->W2t)
__global__ __launch_bounds__(256) void convert_w_kernel(
    const float* __restrict__ W1, const float* __restrict__ W2,
    unsigned short* __restrict__ W1t, unsigned short* __restrict__ W2t)
{
    __shared__ float tile[64][65];
    const float* W = blockIdx.z ? W2 : W1;
    unsigned short* Wt = blockIdx.z ? W2t : W1t;
    const int tx = threadIdx.x, ty = threadIdx.y;
    const int k0 = blockIdx.x * 64, n0 = blockIdx.y * 64;
    for (int r = ty; r < 64; r += 4)
        tile[r][tx] = W[(size_t)(k0 + r) * 256 + n0 + tx];
    __syncthreads();
    for (int r = ty; r < 64; r += 4)
        Wt[(size_t)(n0 + r) * 256 + k0 + tx] = f2bf(tile[tx][r]);
}

// ---- CSR build ----
__global__ __launch_bounds__(256) void count_kernel(
    const int* __restrict__ dst, int* __restrict__ counts)
{
    int e = blockIdx.x * blockDim.x + threadIdx.x;
    if (e < EE) atomicAdd(&counts[dst[e]], 1);
}

// single 1024-thread block; thread t owns counts[10t .. 10t+9]
__global__ __launch_bounds__(1024) void scan_kernel(
    const int* __restrict__ counts,
    int* __restrict__ row_start,
    int* __restrict__ cursor)
{
    __shared__ int wsum[16];
    const int tid = threadIdx.x;
    const int base = tid * 10;
    int v[10];
    int s = 0;
#pragma unroll
    for (int i = 0; i < 10; ++i) {
        const int idx = base + i;
        const int c = (idx < NN) ? counts[idx] : 0;
        s += c;
        v[i] = s;                      // local inclusive
    }
    const int lane = tid & 63, wv = tid >> 6;
    int incl = s;
#pragma unroll
    for (int off = 1; off < 64; off <<= 1) {
        int t = __shfl_up(incl, off, 64);
        if (lane >= off) incl += t;
    }
    if (lane == 63) wsum[wv] = incl;
    __syncthreads();
    if (tid == 0) {
        int r = 0;
#pragma unroll
        for (int i = 0; i < 16; ++i) { int t = wsum[i]; wsum[i] = r; r += t; }
    }
    __syncthreads();
    int run = wsum[wv] + (incl - s);   // exclusive offset of this thread's chunk
#pragma unroll
    for (int i = 0; i < 10; ++i) {
        const int idx = base + i;
        const int c = v[i] - (i ? v[i - 1] : 0);
        if (idx < NN) { row_start[idx] = run; cursor[idx] = run; run += c; }
    }
    if (tid == 0) row_start[NN] = EE;
}

__global__ __launch_bounds__(256) void fill_kernel(
    const int* __restrict__ src, const int* __restrict__ dst,
    int* __restrict__ cursor, int* __restrict__ sorted_src)
{
    int e = blockIdx.x * blockDim.x + threadIdx.x;
    if (e < EE) {
        int p = atomicAdd(&cursor[dst[e]], 1);
        sorted_src[p] = src[e];
    }
}

// ---- gather-sum in bf16: aggb[i] = bf16(x[i] + sum_j x[j]) ----
// one wave per node; lane owns dims [4*lane, 4*lane+4) = 8 bytes bf16
__global__ __launch_bounds__(256) void gather_kernel(
    const unsigned short* __restrict__ xb,
    const int* __restrict__ row_start,
    const int* __restrict__ ssrc,
    unsigned short* __restrict__ aggb)
{
    const int wave = (int)((blockIdx.x * blockDim.x + threadIdx.x) >> 6);
    const int lane = threadIdx.x & 63;
    if (wave >= NN) return;
    const int beg = row_start[wave];
    const int end = row_start[wave + 1];
    const uint2* xv = (const uint2*)xb;

    uint2 self = xv[(size_t)wave * 64 + lane];
    float4 acc;
    acc.x = bf_lo(self.x); acc.y = bf_hi(self.x);
    acc.z = bf_lo(self.y); acc.w = bf_hi(self.y);

    int j = beg;
    for (; j + 3 < end; j += 4) {
        const int s0 = ssrc[j], s1 = ssrc[j + 1], s2 = ssrc[j + 2], s3 = ssrc[j + 3];
        const uint2 v0 = xv[(size_t)s0 * 64 + lane];
        const uint2 v1 = xv[(size_t)s1 * 64 + lane];
        const uint2 v2 = xv[(size_t)s2 * 64 + lane];
        const uint2 v3 = xv[(size_t)s3 * 64 + lane];
        acc.x += bf_lo(v0.x) + bf_lo(v1.x) + bf_lo(v2.x) + bf_lo(v3.x);
        acc.y += bf_hi(v0.x) + bf_hi(v1.x) + bf_hi(v2.x) + bf_hi(v3.x);
        acc.z += bf_lo(v0.y) + bf_lo(v1.y) + bf_lo(v2.y) + bf_lo(v3.y);
        acc.w += bf_hi(v0.y) + bf_hi(v1.y) + bf_hi(v2.y) + bf_hi(v3.y);
    }
    for (; j < end; ++j) {
        const uint2 v0 = xv[(size_t)ssrc[j] * 64 + lane];
        acc.x += bf_lo(v0.x); acc.y += bf_hi(v0.x);
        acc.z += bf_lo(v0.y); acc.w += bf_hi(v0.y);
    }
    unsigned lo = (unsigned)f2bf(acc.x) | ((unsigned)f2bf(acc.y) << 16);
    unsigned hi = (unsigned)f2bf(acc.z) | ((unsigned)f2bf(acc.w) << 16);
    ((uint2*)aggb)[(size_t)wave * 64 + lane] = make_uint2(lo, hi);
}

// ---- bf16 MFMA GEMM: C[M x 256] = act(A @ W + bias) ----
// A bf16 [m][k], Wt bf16 [n][k]. Block = 4 waves, tile 128m x 64n.
// Wave tile 32m x 64n: 2x4 mfma_f32_16x16x32_bf16 accumulators. No LDS.
template <bool RELU, bool OUT_BF16>
__global__ __launch_bounds__(256) void gemm_kernel(
    const unsigned short* __restrict__ A,
    const unsigned short* __restrict__ Wt,
    const float* __restrict__ bias,
    void* __restrict__ Cout, int M)
{
    const int tid = threadIdx.x;
    const int wv = tid >> 6, lane = tid & 63;
    const int quad = lane >> 4, l16 = lane & 15;
    const int n0 = blockIdx.x * 64;
    const int m0 = blockIdx.y * 128 + wv * 32;

    f32x4 acc[2][4] = {};

    int rowA0 = m0 + l16;       if (rowA0 > M - 1) rowA0 = M - 1;
    int rowA1 = m0 + 16 + l16;  if (rowA1 > M - 1) rowA1 = M - 1;
    const short* Ap = (const short*)A;
    const short* Wp = (const short*)Wt;

#pragma unroll
    for (int kk = 0; kk < 256; kk += 32) {
        const int ko = kk + quad * 8;
        const short8 a0 = *(const short8*)(Ap + (size_t)rowA0 * 256 + ko);
        const short8 a1 = *(const short8*)(Ap + (size_t)rowA1 * 256 + ko);
#pragma unroll
        for (int j = 0; j < 4; ++j) {
            const short8 b = *(const short8*)(Wp + (size_t)(n0 + j * 16 + l16) * 256 + ko);
            acc[0][j] = __builtin_amdgcn_mfma_f32_16x16x32_bf16(a0, b, acc[0][j], 0, 0, 0);
            acc[1][j] = __builtin_amdgcn_mfma_f32_16x16x32_bf16(a1, b, acc[1][j], 0, 0, 0);
        }
    }

#pragma unroll
    for (int j = 0; j < 4; ++j) {
        const int col = n0 + j * 16 + l16;
        const float bs = bias[col];
#pragma unroll
        for (int mi = 0; mi < 2; ++mi) {
#pragma unroll
            for (int r = 0; r < 4; ++r) {
                const int row = m0 + mi * 16 + quad * 4 + r;
                if (row < M) {
                    float v = acc[mi][j][r] + bs;
                    if (RELU) v = fmaxf(v, 0.f);
                    if (OUT_BF16)
                        ((unsigned short*)Cout)[(size_t)row * 256 + col] = f2bf(v);
                    else
                        ((float*)Cout)[(size_t)row * 256 + col] = v;
                }
            }
        }
    }
}

extern "C" void kernel_launch(void* const* d_in, const int* in_sizes, int n_in,
                              void* d_out, int out_size, void* d_ws, size_t ws_size,
                              hipStream_t stream)
{
    const float* x   = (const float*)d_in[0];
    const int*   ei  = (const int*)d_in[1];     // [2, E]: src row then dst row
    const float* W1  = (const float*)d_in[2];
    const float* b1  = (const float*)d_in[3];
    const float* W2  = (const float*)d_in[4];
    const float* b2  = (const float*)d_in[5];
    float* out = (float*)d_out;

    const int E = in_sizes[1] / 2;
    const int* src = ei;
    const int* dst = ei + E;

    // Workspace layout (bf16 arrays first; all sizes 8B-multiples)
    unsigned short* xb   = (unsigned short*)d_ws;            // NN*DD bf16
    unsigned short* aggb = xb + (size_t)NN * DD;             // NN*DD bf16
    unsigned short* h1b  = aggb + (size_t)NN * DD;           // NN*DD bf16
    unsigned short* W1t  = h1b + (size_t)NN * DD;            // 256*256 bf16
    unsigned short* W2t  = W1t + 256 * 256;                  // 256*256 bf16
    int* counts     = (int*)(W2t + 256 * 256);               // NN (reused as cursor)
    int* row_start  = counts + NN;                           // NN+1
    int* sorted_src = row_start + NN + 1;                    // EE

    // conversions
    convert_x_kernel<<<(NN * DD / 8 + 255) / 256, 256, 0, stream>>>(x, xb);
    convert_w_kernel<<<dim3(4, 4, 2), dim3(64, 4), 0, stream>>>(W1, W2, W1t, W2t);

    // CSR build
    hipMemsetAsync(counts, 0, NN * sizeof(int), stream);
    count_kernel<<<(EE + 255) / 256, 256, 0, stream>>>(dst, counts);
    scan_kernel<<<1, 1024, 0, stream>>>(counts, row_start, counts);
    fill_kernel<<<(EE + 255) / 256, 256, 0, stream>>>(src, dst, counts, sorted_src);

    // gather-sum (fuses +x), bf16 out
    gather_kernel<<<(NN + 3) / 4, 256, 0, stream>>>(xb, row_start, sorted_src, aggb);

    // MLP via bf16 MFMA
    {
        dim3 grid(DD / 64, (NN + 127) / 128);
        gemm_kernel<true, true><<<grid, 256, 0, stream>>>(aggb, W1t, b1, h1b, NN);
        gemm_kernel<false, false><<<grid, 256, 0, stream>>>(h1b, W2t, b2, out, NN);
    }
    (void)E; (void)ws_size; (void)n_in; (void)out_size;
}

// Round 4
// 172.439 us; speedup vs baseline: 6.9174x; 1.0838x over previous
//
#include <hip/hip_runtime.h>

#define NN 10000
#define EE 320000
#define DD 256

typedef __attribute__((ext_vector_type(8))) short short8;
typedef __attribute__((ext_vector_type(4))) float f32x4;

// ---- bf16 helpers (bit-level, RNE) ----
__device__ __forceinline__ float bf_lo(unsigned u) { return __uint_as_float(u << 16); }
__device__ __forceinline__ float bf_hi(unsigned u) { return __uint_as_float(u & 0xffff0000u); }
__device__ __forceinline__ unsigned short f2bf(float f) {
    unsigned u = __float_as_uint(f);
    u += 0x7fffu + ((u >> 16) & 1u);   // round-to-nearest-even
    return (unsigned short)(u >> 16);
}

// ---- fused prep: convert x -> bf16 | convert+transpose W -> bf16 | count ----
// blocks [0,1250): convert_x (8 elems/thread)
// blocks [1250,1282): convert W1/W2 [k][n] fp32 -> Wt [n][k] bf16 (64x64 tiles)
// blocks [1282,2532): histogram of dst
__global__ __launch_bounds__(256) void prep_kernel(
    const float* __restrict__ x, unsigned short* __restrict__ xb,
    const float* __restrict__ W1, const float* __restrict__ W2,
    unsigned short* __restrict__ W1t, unsigned short* __restrict__ W2t,
    const int* __restrict__ dst, int* __restrict__ counts)
{
    __shared__ float tile[64][65];
    const int bid = blockIdx.x;
    const int tid = threadIdx.x;
    if (bid < 1250) {
        const int i = bid * 2048 + tid * 8;
        const float4 a = *(const float4*)(x + i);
        const float4 b = *(const float4*)(x + i + 4);
        unsigned short o[8] = {f2bf(a.x), f2bf(a.y), f2bf(a.z), f2bf(a.w),
                               f2bf(b.x), f2bf(b.y), f2bf(b.z), f2bf(b.w)};
        *(short8*)(xb + i) = *(short8*)o;
    } else if (bid < 1282) {
        int wid = bid - 1250;
        const float* W = (wid & 16) ? W2 : W1;
        unsigned short* Wt = (wid & 16) ? W2t : W1t;
        wid &= 15;
        const int k0 = (wid & 3) * 64, n0 = (wid >> 2) * 64;
        const int tx = tid & 63, ty = tid >> 6;
        for (int r = ty; r < 64; r += 4)
            tile[r][tx] = W[(size_t)(k0 + r) * 256 + n0 + tx];
        __syncthreads();
        for (int r = ty; r < 64; r += 4)
            Wt[(size_t)(n0 + r) * 256 + k0 + tx] = f2bf(tile[tx][r]);
    } else {
        const int e = (bid - 1282) * 256 + tid;
        if (e < EE) atomicAdd(&counts[dst[e]], 1);
    }
}

// ---- scan: single 1024-thread block; thread t owns counts[10t .. 10t+9] ----
__global__ __launch_bounds__(1024) void scan_kernel(
    const int* __restrict__ counts,
    int* __restrict__ row_start,
    int* __restrict__ cursor)
{
    __shared__ int wsum[16];
    const int tid = threadIdx.x;
    const int base = tid * 10;
    int v[10];
    int s = 0;
#pragma unroll
    for (int i = 0; i < 10; ++i) {
        const int idx = base + i;
        const int c = (idx < NN) ? counts[idx] : 0;
        s += c;
        v[i] = s;                      // local inclusive
    }
    const int lane = tid & 63, wv = tid >> 6;
    int incl = s;
#pragma unroll
    for (int off = 1; off < 64; off <<= 1) {
        int t = __shfl_up(incl, off, 64);
        if (lane >= off) incl += t;
    }
    if (lane == 63) wsum[wv] = incl;
    __syncthreads();
    if (tid == 0) {
        int r = 0;
#pragma unroll
        for (int i = 0; i < 16; ++i) { int t = wsum[i]; wsum[i] = r; r += t; }
    }
    __syncthreads();
    int run = wsum[wv] + (incl - s);   // exclusive offset of this thread's chunk
#pragma unroll
    for (int i = 0; i < 10; ++i) {
        const int idx = base + i;
        const int c = v[i] - (i ? v[i - 1] : 0);
        if (idx < NN) { row_start[idx] = run; cursor[idx] = run; run += c; }
    }
    if (tid == 0) row_start[NN] = EE;
}

__global__ __launch_bounds__(256) void fill_kernel(
    const int* __restrict__ src, const int* __restrict__ dst,
    int* __restrict__ cursor, int* __restrict__ sorted_src)
{
    int e = blockIdx.x * blockDim.x + threadIdx.x;
    if (e < EE) {
        int p = atomicAdd(&cursor[dst[e]], 1);
        sorted_src[p] = src[e];
    }
}

// ---- gather-sum in bf16: aggb[i] = bf16(x[i] + sum_j x[j]) ----
// one wave per node; lane owns dims [4*lane, 4*lane+4) = 8 bytes bf16
__global__ __launch_bounds__(256) void gather_kernel(
    const unsigned short* __restrict__ xb,
    const int* __restrict__ row_start,
    const int* __restrict__ ssrc,
    unsigned short* __restrict__ aggb)
{
    const int wave = (int)((blockIdx.x * blockDim.x + threadIdx.x) >> 6);
    const int lane = threadIdx.x & 63;
    if (wave >= NN) return;
    const int beg = row_start[wave];
    const int end = row_start[wave + 1];
    const uint2* xv = (const uint2*)xb;

    uint2 self = xv[(size_t)wave * 64 + lane];
    float4 acc;
    acc.x = bf_lo(self.x); acc.y = bf_hi(self.x);
    acc.z = bf_lo(self.y); acc.w = bf_hi(self.y);

    int j = beg;
    for (; j + 3 < end; j += 4) {
        const int s0 = ssrc[j], s1 = ssrc[j + 1], s2 = ssrc[j + 2], s3 = ssrc[j + 3];
        const uint2 v0 = xv[(size_t)s0 * 64 + lane];
        const uint2 v1 = xv[(size_t)s1 * 64 + lane];
        const uint2 v2 = xv[(size_t)s2 * 64 + lane];
        const uint2 v3 = xv[(size_t)s3 * 64 + lane];
        acc.x += bf_lo(v0.x) + bf_lo(v1.x) + bf_lo(v2.x) + bf_lo(v3.x);
        acc.y += bf_hi(v0.x) + bf_hi(v1.x) + bf_hi(v2.x) + bf_hi(v3.x);
        acc.z += bf_lo(v0.y) + bf_lo(v1.y) + bf_lo(v2.y) + bf_lo(v3.y);
        acc.w += bf_hi(v0.y) + bf_hi(v1.y) + bf_hi(v2.y) + bf_hi(v3.y);
    }
    for (; j < end; ++j) {
        const uint2 v0 = xv[(size_t)ssrc[j] * 64 + lane];
        acc.x += bf_lo(v0.x); acc.y += bf_hi(v0.x);
        acc.z += bf_lo(v0.y); acc.w += bf_hi(v0.y);
    }
    unsigned lo = (unsigned)f2bf(acc.x) | ((unsigned)f2bf(acc.y) << 16);
    unsigned hi = (unsigned)f2bf(acc.z) | ((unsigned)f2bf(acc.w) << 16);
    ((uint2*)aggb)[(size_t)wave * 64 + lane] = make_uint2(lo, hi);
}

// ---- fused MLP: out = (relu(agg @ W1 + b1)) @ W2 + b2 ----
// 32 rows per block, 4 waves; wave w owns n-slice [64w, 64w+64).
// GEMM1 reads A from global, writes relu'd h1 (bf16) to LDS; GEMM2 reads LDS.
__global__ __launch_bounds__(256) void mlp_kernel(
    const unsigned short* __restrict__ aggb,
    const unsigned short* __restrict__ W1t,
    const unsigned short* __restrict__ W2t,
    const float* __restrict__ b1,
    const float* __restrict__ b2,
    float* __restrict__ out, int M)
{
    __shared__ unsigned short h1[32][264];   // +8 pad, keeps 16B alignment
    const int tid = threadIdx.x;
    const int wv = tid >> 6, lane = tid & 63;
    const int quad = lane >> 4, l16 = lane & 15;
    const int m0 = blockIdx.x * 32;
    const int n0 = wv * 64;

    int rowA0 = m0 + l16;       if (rowA0 > M - 1) rowA0 = M - 1;
    int rowA1 = m0 + 16 + l16;  if (rowA1 > M - 1) rowA1 = M - 1;
    const short* Ap  = (const short*)aggb;
    const short* W1p = (const short*)W1t;
    const short* W2p = (const short*)W2t;

    f32x4 acc[2][4] = {};
#pragma unroll
    for (int kk = 0; kk < 256; kk += 32) {
        const int ko = kk + quad * 8;
        const short8 a0 = *(const short8*)(Ap + (size_t)rowA0 * 256 + ko);
        const short8 a1 = *(const short8*)(Ap + (size_t)rowA1 * 256 + ko);
#pragma unroll
        for (int j = 0; j < 4; ++j) {
            const short8 b = *(const short8*)(W1p + (size_t)(n0 + j * 16 + l16) * 256 + ko);
            acc[0][j] = __builtin_amdgcn_mfma_f32_16x16x32_bf16(a0, b, acc[0][j], 0, 0, 0);
            acc[1][j] = __builtin_amdgcn_mfma_f32_16x16x32_bf16(a1, b, acc[1][j], 0, 0, 0);
        }
    }
#pragma unroll
    for (int j = 0; j < 4; ++j) {
        const int col = n0 + j * 16 + l16;
        const float bs = b1[col];
#pragma unroll
        for (int mi = 0; mi < 2; ++mi)
#pragma unroll
            for (int r = 0; r < 4; ++r) {
                const int row = mi * 16 + quad * 4 + r;
                h1[row][col] = f2bf(fmaxf(acc[mi][j][r] + bs, 0.f));
            }
    }
    __syncthreads();

    f32x4 acc2[2][4] = {};
#pragma unroll
    for (int kk = 0; kk < 256; kk += 32) {
        const int ko = kk + quad * 8;
        const short8 a0 = *(const short8*)&h1[l16][ko];
        const short8 a1 = *(const short8*)&h1[16 + l16][ko];
#pragma unroll
        for (int j = 0; j < 4; ++j) {
            const short8 b = *(const short8*)(W2p + (size_t)(n0 + j * 16 + l16) * 256 + ko);
            acc2[0][j] = __builtin_amdgcn_mfma_f32_16x16x32_bf16(a0, b, acc2[0][j], 0, 0, 0);
            acc2[1][j] = __builtin_amdgcn_mfma_f32_16x16x32_bf16(a1, b, acc2[1][j], 0, 0, 0);
        }
    }
#pragma unroll
    for (int j = 0; j < 4; ++j) {
        const int col = n0 + j * 16 + l16;
        const float bs = b2[col];
#pragma unroll
        for (int mi = 0; mi < 2; ++mi)
#pragma unroll
            for (int r = 0; r < 4; ++r) {
                const int row = m0 + mi * 16 + quad * 4 + r;
                if (row < M)
                    out[(size_t)row * 256 + col] = acc2[mi][j][r] + bs;
            }
    }
}

extern "C" void kernel_launch(void* const* d_in, const int* in_sizes, int n_in,
                              void* d_out, int out_size, void* d_ws, size_t ws_size,
                              hipStream_t stream)
{
    const float* x   = (const float*)d_in[0];
    const int*   ei  = (const int*)d_in[1];     // [2, E]: src row then dst row
    const float* W1  = (const float*)d_in[2];
    const float* b1  = (const float*)d_in[3];
    const float* W2  = (const float*)d_in[4];
    const float* b2  = (const float*)d_in[5];
    float* out = (float*)d_out;

    const int E = in_sizes[1] / 2;
    const int* src = ei;
    const int* dst = ei + E;

    // Workspace layout
    unsigned short* xb   = (unsigned short*)d_ws;            // NN*DD bf16
    unsigned short* aggb = xb + (size_t)NN * DD;             // NN*DD bf16
    unsigned short* W1t  = aggb + (size_t)NN * DD;           // 256*256 bf16
    unsigned short* W2t  = W1t + 256 * 256;                  // 256*256 bf16
    int* counts     = (int*)(W2t + 256 * 256);               // NN (reused as cursor)
    int* row_start  = counts + NN;                           // NN+1
    int* sorted_src = row_start + NN + 1;                    // EE

    hipMemsetAsync(counts, 0, NN * sizeof(int), stream);
    prep_kernel<<<2532, 256, 0, stream>>>(x, xb, W1, W2, W1t, W2t, dst, counts);
    scan_kernel<<<1, 1024, 0, stream>>>(counts, row_start, counts);
    fill_kernel<<<(EE + 255) / 256, 256, 0, stream>>>(src, dst, counts, sorted_src);
    gather_kernel<<<(NN + 3) / 4, 256, 0, stream>>>(xb, row_start, sorted_src, aggb);
    mlp_kernel<<<(NN + 31) / 32, 256, 0, stream>>>(aggb, W1t, W2t, b1, b2, out, NN);

    (void)E; (void)ws_size; (void)n_in; (void)out_size;
}